// Round 4
// baseline (150.263 us; speedup 1.0000x reference)
//
#include <hip/hip_runtime.h>

// out[b*Lp + p, c, k] = x[b, c, p + k]
// B=128, C=4, L=2048, K=200, Lp=1849. 757 MB written -> write-bound.
// 4 phase-shifted LDS copies (copy phi slot m = x[p0+phi+4m .. +3]) so each
// output float4 is one ds_read_b128. NEW in this round: fully decouple the
// store stream from the LDS reads -- prefetch all 25 float4 per thread into
// registers, then issue 25 dependency-free stores (memset-like burst, no
// lgkm/WAR waits inside), targeting the 6.7 TB/s write rate the fills hit.

#define B_     128
#define C_     4
#define L_     2048
#define K_     200
#define LP_    1849
#define TP_    32              // p-rows per full tile
#define NT_    58              // 57 full tiles + 1 tail tile of 25 rows
#define TAIL_  25              // 1849 - 57*32
#define NSLOT_ 57              // float4 slots per (copy, channel)
#define NITER_ 25              // 32*200/256 store float4s per thread (full tile)

__global__ __launch_bounds__(256, 1) void unfold_burst(const float* __restrict__ x,
                                                       float* __restrict__ out)
{
    __shared__ float4 lds[16 * NSLOT_];   // 4 copies * 4 channels * 57 (14.6 KB)

    unsigned int blk = blockIdx.x;
    unsigned int b   = blk / NT_;
    unsigned int t   = blk - b * NT_;
    unsigned int p0  = t * TP_;
    unsigned int rows = (t == NT_ - 1) ? TAIL_ : TP_;

    // ---- Stage: task tau = (c, m). Load x[c][p0+4m .. +7], emit 4 shifted copies.
    unsigned int tau = threadIdx.x;
    if (tau < 4u * NSLOT_) {
        unsigned int c = tau / NSLOT_;
        unsigned int m = tau - c * NSLOT_;
        const float* row = x + (size_t)(b * 4u + c) * L_;
        unsigned int g = p0 + 4u * m;
        float v0x, v0y, v0z, v0w, v1x, v1y, v1z;
        if (g + 7u <= (unsigned)(L_ - 1)) {
            float4 v0 = *reinterpret_cast<const float4*>(row + g);
            float4 v1 = *reinterpret_cast<const float4*>(row + g + 4);
            v0x = v0.x; v0y = v0.y; v0z = v0.z; v0w = v0.w;
            v1x = v1.x; v1y = v1.y; v1z = v1.z;
        } else {
            v0x = row[min(g + 0u, 2047u)];
            v0y = row[min(g + 1u, 2047u)];
            v0z = row[min(g + 2u, 2047u)];
            v0w = row[min(g + 3u, 2047u)];
            v1x = row[min(g + 4u, 2047u)];
            v1y = row[min(g + 5u, 2047u)];
            v1z = row[min(g + 6u, 2047u)];
        }
        lds[(0u * 4u + c) * NSLOT_ + m] = make_float4(v0x, v0y, v0z, v0w);
        lds[(1u * 4u + c) * NSLOT_ + m] = make_float4(v0y, v0z, v0w, v1x);
        lds[(2u * 4u + c) * NSLOT_ + m] = make_float4(v0z, v0w, v1x, v1y);
        lds[(3u * 4u + c) * NSLOT_ + m] = make_float4(v0w, v1x, v1y, v1z);
    }
    __syncthreads();

    float4* out4 = reinterpret_cast<float4*>(out) + (size_t)(b * LP_ + p0) * 200u;

    if (rows == TP_) {
        // ---- Prefetch the whole per-thread tile into registers (static idx).
        float4 v[NITER_];
#pragma unroll
        for (int n = 0; n < NITER_; ++n) {
            unsigned int i  = threadIdx.x + 256u * (unsigned)n;
            unsigned int p  = i / 200u;
            unsigned int r  = i - p * 200u;
            unsigned int c  = r / 50u;
            unsigned int k4 = r - c * 50u;
            v[n] = lds[((p & 3u) * 4u + c) * NSLOT_ + (p >> 2u) + k4];
        }
        // ---- Pure store burst: 25 dependency-free dwordx4 stores.
#pragma unroll
        for (int n = 0; n < NITER_; ++n) {
            out4[threadIdx.x + 256u * (unsigned)n] = v[n];
        }
    } else {
        // tail tile (128 blocks): simple guarded loop
        unsigned int n4 = rows * 200u;    // 5000
        for (unsigned int i = threadIdx.x; i < n4; i += 256u) {
            unsigned int p  = i / 200u;
            unsigned int r  = i - p * 200u;
            unsigned int c  = r / 50u;
            unsigned int k4 = r - c * 50u;
            out4[i] = lds[((p & 3u) * 4u + c) * NSLOT_ + (p >> 2u) + k4];
        }
    }
}

extern "C" void kernel_launch(void* const* d_in, const int* in_sizes, int n_in,
                              void* d_out, int out_size, void* d_ws, size_t ws_size,
                              hipStream_t stream)
{
    const float* x = (const float*)d_in[0];
    float* out = (float*)d_out;

    int grid = B_ * NT_;   // 7424 blocks, each writes 102.4 KB contiguous
    unfold_burst<<<grid, 256, 0, stream>>>(x, out);
}